// Round 1
// 1494.100 us; speedup vs baseline: 1.9924x; 1.9924x over previous
//
#include <hip/hip_runtime.h>
#include <math.h>

typedef unsigned int u32;
typedef unsigned short u16;
typedef unsigned long long u64;

#define BATCH 64
#define A_TOT 8649
#define TOPN  6000
#define POST  1500
#define NB    4096
#define NT    512
#define NSLOT 12
#define NOACT 0xFFFFFFFFu

// LDS layout (bytes), lifetimes disjoint where overlapping:
//   [0,      69192)  keys   u64[8649]   (keys[0..6000) = [0,48000) live to the end)
//   [48000, 144000)  boxes  float4[6000] (written in decode; overlaps dead keys tail+buckets)
//   [69632,  86016)  bucketA u32[4096]  (sort only; disjoint from keys)
//   [86016, 102400)  bucketB u32[4096]  (sort only)
//   [102400,106496)  stemp  u32[1024]   (scan only)
//   [144000,156000)  pp     u16[6000]   (pick position per candidate)
//   [156000,156064)  wmin   u32[2][8]   (per-wave argmin, double-buffered)
#define LDS_BYTES 156064

__global__ __launch_bounds__(NT, 2) void roibbox_kernel(
    const float* __restrict__ deltas,    // [B, A, 4]
    const float* __restrict__ probs,     // [B, A]
    const float* __restrict__ anchors,   // [A, 4]
    float* __restrict__ out)             // [B*POST*4] boxes then [B*POST] scores
{
    #pragma clang fp contract(off)
    __shared__ alignas(16) char smem[LDS_BYTES];
    u64*    keysL   = (u64*)   (smem + 0);
    float4* boxes4  = (float4*)(smem + 48000);
    u32*    bucketA = (u32*)   (smem + 69632);
    u32*    bucketB = (u32*)   (smem + 86016);
    u32*    stemp   = (u32*)   (smem + 102400);
    u16*    ppL     = (u16*)   (smem + 144000);
    u32*    wminL   = (u32*)   (smem + 156000);

    const int tid = threadIdx.x;
    const int b   = blockIdx.x;
    const float* pb = probs + (size_t)b * A_TOT;

    // ---------- init ----------
    #pragma unroll
    for (int i = 0; i < NB/NT; ++i) bucketA[tid + i*NT] = 0u;
    __syncthreads();

    // ---------- histogram (bucket by score; reversed so bucket 0 = highest) ----------
    for (int j = tid; j < A_TOT; j += NT) {
        float s = pb[j];
        int bkt = (int)(s * (float)NB);
        bkt = (NB-1) - min(max(bkt, 0), NB-1);
        atomicAdd(&bucketA[bkt], 1u);
    }
    __syncthreads();

    // ---------- exclusive scan over 4096 counts (8 per thread + Hillis-Steele) ----------
    {
        int base8 = tid << 3;
        u32 c[8]; u32 ms = 0;
        #pragma unroll
        for (int i = 0; i < 8; ++i) { c[i] = bucketA[base8+i]; ms += c[i]; }
        stemp[tid] = ms;
        __syncthreads();
        int src = 0;
        for (int off = 1; off < NT; off <<= 1) {
            u32 v = stemp[src*NT + tid];
            if (tid >= off) v += stemp[src*NT + tid - off];
            stemp[(src^1)*NT + tid] = v;
            __syncthreads();
            src ^= 1;
        }
        u32 excl = stemp[src*NT + tid] - ms;
        #pragma unroll
        for (int i = 0; i < 8; ++i) {
            bucketA[base8+i] = excl; bucketB[base8+i] = excl; excl += c[i];
        }
    }
    __syncthreads();

    // ---------- scatter keys into LDS ----------
    for (int j = tid; j < A_TOT; j += NT) {
        float s = pb[j];
        int bkt = (int)(s * (float)NB);
        bkt = (NB-1) - min(max(bkt, 0), NB-1);
        u32 pos = atomicAdd(&bucketB[bkt], 1u);
        keysL[pos] = ((u64)__float_as_uint(s) << 32) | (u64)(~(u32)j);
    }
    __syncthreads();

    // ---------- per-bucket insertion sort (descending; keys unique) ----------
    for (int bkt = tid; bkt < NB; bkt += NT) {
        int begin = (int)bucketA[bkt], end = (int)bucketB[bkt];
        for (int k = begin + 1; k < end; ++k) {
            u64 key = keysL[k];
            int m = k - 1;
            while (m >= begin && keysL[m] < key) { keysL[m+1] = keysL[m]; --m; }
            keysL[m+1] = key;
        }
    }
    __syncthreads();

    // ---------- decode: thread t owns score-ranks [12t, 12t+12) ----------
    float ry1[NSLOT], rx1[NSLOT], ry2[NSLOT], rx2[NSLOT], rA[NSLOT];
    u32 mask = 0;
    const u32 base = (u32)tid * NSLOT;
    if (tid < TOPN / NSLOT) {              // 500 threads * 12 = 6000, exact
        #pragma unroll
        for (int i = 0; i < NSLOT; ++i) {
            int j = (int)base + i;
            u64 k = keysL[j];
            u32 aidx = ~((u32)k);
            float4 av = *(const float4*)(anchors + (size_t)aidx * 4);
            float4 dv = *(const float4*)(deltas + ((size_t)b * A_TOT + aidx) * 4);
            float d0 = dv.x*0.1f, d1 = dv.y*0.1f, d2 = dv.z*0.2f, d3 = dv.w*0.2f;
            float ah = av.z - av.x, aw = av.w - av.y;
            float acy = av.x + 0.5f*ah, acx = av.y + 0.5f*aw;
            float h = (float)exp((double)d2) * ah;   // correctly-rounded fp32 exp
            float w = (float)exp((double)d3) * aw;
            float cy = d0*ah + acy;                  // contract(off): mul then add
            float cx = d1*aw + acx;
            ry1[i] = cy - 0.5f*h; rx1[i] = cx - 0.5f*w;
            ry2[i] = cy + 0.5f*h; rx2[i] = cx + 0.5f*w;
            rA[i]  = (ry2[i]-ry1[i])*(rx2[i]-rx1[i]);
            boxes4[j] = make_float4(ry1[i], rx1[i], ry2[i], rx2[i]);
        }
        mask = (1u << NSLOT) - 1u;
    } else {
        #pragma unroll
        for (int i = 0; i < NSLOT; ++i) { ry1[i]=0.f; rx1[i]=0.f; ry2[i]=0.f; rx2[i]=0.f; rA[i]=0.f; }
    }
    // init pick-position table
    for (int j = tid; j < TOPN/2; j += NT) ((u32*)ppL)[j] = 0xFFFFFFFFu;
    __syncthreads();

    // ---------- greedy NMS: 1 barrier/pick ----------
    // suppress iff fl32(inter/den) > 0.7f  <=>  inter >= M*den exactly (M = RNE boundary)
    const double MTHR = (double)0.7f + 0x1p-25;
    const u32 lane = (u32)tid & 63u;
    const u32 wv   = (u32)tid >> 6;
    u32 cur = 0;                         // rank 0 is always the first pick
    int pend = POST;

    for (int p = 0; p < POST; ++p) {
        u32* wslot = wminL + (p & 1) * 8;          // double-buffered per-wave mins
        u64 anyb = __ballot(mask != 0u);
        if (anyb != 0ull) {                        // wave-uniform: skip dead waves
            if (cur - base < (u32)NSLOT) ppL[cur] = (u16)p;   // owner records pick pos
            float4 sb = boxes4[cur];               // same-address broadcast read
            float sA = (sb.z - sb.x) * (sb.w - sb.y);   // == stored rA bit-exactly
            #pragma unroll
            for (int i = 0; i < NSLOT; ++i) {      // branchless suppress
                float yy1 = fmaxf(sb.x, ry1[i]);
                float xx1 = fmaxf(sb.y, rx1[i]);
                float yy2 = fminf(sb.z, ry2[i]);
                float xx2 = fminf(sb.w, rx2[i]);
                float inter = fmaxf(yy2 - yy1, 0.0f) * fmaxf(xx2 - xx1, 0.0f);
                float den = ((sA + rA[i]) - inter) + 1e-9f;   // exact ref order
                if ((double)inter >= MTHR * (double)den) mask &= ~(1u << i);
            }
            u64 bal = __ballot(mask != 0u);
            if (mask != 0u) {
                if (lane == (u32)__builtin_ctzll(bal))       // first active lane
                    wslot[wv] = base + (u32)__builtin_ctz(mask);
            } else if (bal == 0ull) {
                if (lane == 0u) wslot[wv] = NOACT;           // wave died this pick
            }
        } else {
            if (lane == 0u) wslot[wv] = NOACT;               // permanently dead wave
        }
        __syncthreads();                 // the only barrier per pick
        uint4 wa = *((const uint4*)wslot);
        uint4 wb = *((const uint4*)(wslot + 4));
        u32 g = min(min(min(wa.x, wa.y), min(wa.z, wa.w)),
                    min(min(wb.x, wb.y), min(wb.z, wb.w)));
        if (g == NOACT) { pend = p + 1; break; }  // uniform: no survivors
        cur = g;
    }

    // ---------- epilogue: deferred output writes ----------
    const size_t sbase = (size_t)BATCH * POST * 4;
    if (tid < TOPN / NSLOT) {
        #pragma unroll
        for (int i = 0; i < NSLOT; ++i) {
            u32 v = (u32)ppL[base + i];
            if (v != 0xFFFFu) {
                size_t row = (size_t)b * POST + v;
                float* ob = out + row * 4;
                ob[0] = fminf(fmaxf(ry1[i], 0.f), 1.f);
                ob[1] = fminf(fmaxf(rx1[i], 0.f), 1.f);
                ob[2] = fminf(fmaxf(ry2[i], 0.f), 1.f);
                ob[3] = fminf(fmaxf(rx2[i], 0.f), 1.f);
                out[sbase + row] = __uint_as_float((u32)(keysL[base + i] >> 32));
            }
        }
    }
    for (int r = pend + tid; r < POST; r += NT) {
        size_t row = (size_t)b * POST + r;
        float* ob = out + row * 4;
        ob[0]=0.f; ob[1]=0.f; ob[2]=0.f; ob[3]=0.f;
        out[sbase + row] = 0.f;
    }
}

extern "C" void kernel_launch(void* const* d_in, const int* in_sizes, int n_in,
                              void* d_out, int out_size, void* d_ws, size_t ws_size,
                              hipStream_t stream) {
    const float* deltas  = (const float*)d_in[0];  // [64,31,31,36] f32
    const float* probs   = (const float*)d_in[1];  // [64,31,31,9]  f32
    // d_in[2] = gt_labels (unused)
    const float* anchors = (const float*)d_in[3];  // [8649,4] f32
    float* out = (float*)d_out;                    // 480000 f32
    // d_ws unused: keys/sort fully LDS-resident now

    roibbox_kernel<<<dim3(BATCH), dim3(NT), 0, stream>>>(deltas, probs, anchors, out);
}